// Round 8
// baseline (81.361 us; speedup 1.0000x reference)
//
#include <hip/hip_runtime.h>
#include <hip/hip_bf16.h>
#include <math.h>

#define S        8192
#define D        8
#define EPSF     1e-6f
#define LOG2E    1.442695040888963f
#define EPS_S    (LOG2E * EPSF)
#define NT       512        // 8192/16 tiles per dim

// ws byte offsets
#define ZHL_OFF  0          // 8192 rows x 16 ushort (hi[8]|lo[8]) = 262144 B
#define U_OFF    262144     // 8192 f32
#define V_OFF    294912     // 8192 f32
#define ACC_OFF  327680     // double dsum, double ssum, uint counter

#define NSBLK    256        // sparse blocks
#define NDBLK    2048       // dense blocks = 256 row-pairs x 8
#define NBLK     (NSBLK + NDBLK)
#define NWPP     32         // waves per row-pair

typedef __attribute__((ext_vector_type(8))) short short8_t;
typedef __attribute__((ext_vector_type(4))) float f32x4;

__device__ __forceinline__ float block_reduce_f(float v, float* sm) {
    #pragma unroll
    for (int off = 32; off > 0; off >>= 1) v += __shfl_down(v, off, 64);
    int lane = threadIdx.x & 63, wid = threadIdx.x >> 6;
    if (lane == 0) sm[wid] = v;
    __syncthreads();
    float s = 0.f;
    if (threadIdx.x == 0) {
        for (int w = 0; w < 4; ++w) s += sm[w];
    }
    return s;
}

// ---- kernel 1: gather + prescale + bf16 hi/lo split; zero accumulators ----
__global__ __launch_bounds__(256) void gather_kernel(const float* __restrict__ Z,
                                                     const int* __restrict__ idx,
                                                     ushort* __restrict__ zhl,
                                                     float* __restrict__ u,
                                                     float* __restrict__ v,
                                                     double* __restrict__ dsum,
                                                     double* __restrict__ ssum,
                                                     unsigned int* __restrict__ counter) {
    int t = blockIdx.x * 256 + threadIdx.x;
    if (t == 0) { *dsum = 0.0; *ssum = 0.0; *counter = 0u; }
    if (t >= S) return;
    int n = idx[t];
    const float4* zp = (const float4*)(Z + (size_t)n * D);
    float4 a = zp[0], b = zp[1];
    float z[8] = { a.x, a.y, a.z, a.w, b.x, b.y, b.z, b.w };
    float ss = 0.f;
    short8_t h, l;
    #pragma unroll
    for (int k = 0; k < 8; ++k) {
        float zs = LOG2E * z[k];
        ss = fmaf(zs, zs, ss);
        __hip_bfloat16 hb = __float2bfloat16(zs);
        float hf = __bfloat162float(hb);
        __hip_bfloat16 lb = __float2bfloat16(zs - hf);
        h[k] = (short)__builtin_bit_cast(unsigned short, hb);
        l[k] = (short)__builtin_bit_cast(unsigned short, lb);
    }
    *(short8_t*)(zhl + (size_t)t * 16)     = h;
    *(short8_t*)(zhl + (size_t)t * 16 + 8) = l;
    u[t] = ss + 8.f * EPS_S * EPS_S;
    v[t] = ss;
}

// Sweep `cnt` consecutive j-tiles starting at tj0 for fixed i-tile ti.
// Off-diagonal tiles weight 2 (mirror not enumerated), diagonal tile weight 1.
// Depth-2 register prefetch of the B fragment + v.
__device__ __forceinline__ void dense_sweep(const ushort* __restrict__ zhl,
                                            const float* __restrict__ v,
                                            short8_t afrag, float4 u4, int boff,
                                            int ti, int tj0, int cnt, int r,
                                            float& ax, float& ay, float& az, float& aw) {
    const ushort* bp = zhl + (size_t)(tj0 * 16 + r) * 16 + boff;
    const float*  vp = v + tj0 * 16 + r;
    short8_t b0 = *(const short8_t*)bp;
    float    v0 = vp[0];
    short8_t b1 = b0;
    float    v1 = v0;
    if (cnt > 1) { b1 = *(const short8_t*)(bp + 256); v1 = vp[16]; }
    #pragma unroll 2
    for (int t = 0; t < cnt; ++t) {
        short8_t bcur = b0;
        float    vcur = v0;
        b0 = b1; v0 = v1;
        if (t + 2 < cnt) {
            b1 = *(const short8_t*)(bp + (size_t)(t + 2) * 256);
            v1 = vp[(t + 2) * 16];
        }
        float w = (tj0 + t == ti) ? 1.f : 2.f;
        f32x4 c = { 0.f, 0.f, 0.f, 0.f };
        c = __builtin_amdgcn_mfma_f32_16x16x32_bf16(afrag, bcur, c, 0, 0, 0);
        float d2_0 = fmaf(c[0], -2.f, u4.x + vcur);
        float d2_1 = fmaf(c[1], -2.f, u4.y + vcur);
        float d2_2 = fmaf(c[2], -2.f, u4.z + vcur);
        float d2_3 = fmaf(c[3], -2.f, u4.w + vcur);
        ax = fmaf(w, __builtin_amdgcn_exp2f(-__builtin_amdgcn_sqrtf(__builtin_fabsf(d2_0))), ax);
        ay = fmaf(w, __builtin_amdgcn_exp2f(-__builtin_amdgcn_sqrtf(__builtin_fabsf(d2_1))), ay);
        az = fmaf(w, __builtin_amdgcn_exp2f(-__builtin_amdgcn_sqrtf(__builtin_fabsf(d2_2))), az);
        aw = fmaf(w, __builtin_amdgcn_exp2f(-__builtin_amdgcn_sqrtf(__builtin_fabsf(d2_3))), aw);
    }
}

// ---- kernel 2: sparse (blocks < NSBLK) || dense triangle (rest); the last
// arriving block composes the scalar output. ----
__global__ __launch_bounds__(256) void fused_kernel(
        const ushort* __restrict__ zhl, const float* __restrict__ u,
        const float* __restrict__ v, const float* __restrict__ Z,
        const int* __restrict__ ei, const int* __restrict__ ej, int ne,
        const float* __restrict__ alpha, double* __restrict__ dsum,
        double* __restrict__ ssum, unsigned int* __restrict__ counter,
        float* __restrict__ out) {
    __shared__ float red[4];
    int tid = threadIdx.x, bx = blockIdx.x;

    if (bx < NSBLK) {
        // ---- sparse positive-edge term ----
        float acc = 0.f;
        int nchunk = ne >> 2;
        for (int c = bx * 256 + tid; c < nchunk; c += NSBLK * 256) {
            int4 ia = ((const int4*)ei)[c];
            int4 ib = ((const int4*)ej)[c];
            int aidx[4] = { ia.x, ia.y, ia.z, ia.w };
            int bidx[4] = { ib.x, ib.y, ib.z, ib.w };
            #pragma unroll
            for (int q = 0; q < 4; ++q) {
                const float4* za = (const float4*)(Z + (size_t)aidx[q] * D);
                const float4* zb = (const float4*)(Z + (size_t)bidx[q] * D);
                float4 a0 = za[0], a1 = za[1];
                float4 b0 = zb[0], b1 = zb[1];
                float d0 = a0.x - b0.x + EPSF;
                float d1 = a0.y - b0.y + EPSF;
                float d2 = a0.z - b0.z + EPSF;
                float d3 = a0.w - b0.w + EPSF;
                float d4 = a1.x - b1.x + EPSF;
                float d5 = a1.y - b1.y + EPSF;
                float d6 = a1.z - b1.z + EPSF;
                float d7 = a1.w - b1.w + EPSF;
                float s2 = d0 * d0;
                s2 = fmaf(d1, d1, s2);
                s2 = fmaf(d2, d2, s2);
                s2 = fmaf(d3, d3, s2);
                s2 = fmaf(d4, d4, s2);
                s2 = fmaf(d5, d5, s2);
                s2 = fmaf(d6, d6, s2);
                s2 = fmaf(d7, d7, s2);
                acc += __builtin_amdgcn_sqrtf(s2);
            }
        }
        for (int e = (nchunk << 2) + bx * 256 + tid; e < ne; e += NSBLK * 256) {
            int a = ei[e], b = ej[e];
            const float4* za = (const float4*)(Z + (size_t)a * D);
            const float4* zb = (const float4*)(Z + (size_t)b * D);
            float4 a0 = za[0], a1 = za[1];
            float4 b0 = zb[0], b1 = zb[1];
            float d0 = a0.x - b0.x + EPSF, d1 = a0.y - b0.y + EPSF;
            float d2 = a0.z - b0.z + EPSF, d3 = a0.w - b0.w + EPSF;
            float d4 = a1.x - b1.x + EPSF, d5 = a1.y - b1.y + EPSF;
            float d6 = a1.z - b1.z + EPSF, d7 = a1.w - b1.w + EPSF;
            float s2 = d0 * d0;
            s2 = fmaf(d1, d1, s2); s2 = fmaf(d2, d2, s2); s2 = fmaf(d3, d3, s2);
            s2 = fmaf(d4, d4, s2); s2 = fmaf(d5, d5, s2); s2 = fmaf(d6, d6, s2);
            s2 = fmaf(d7, d7, s2);
            acc += __builtin_amdgcn_sqrtf(s2);
        }
        float s = block_reduce_f(acc, red);
        if (tid == 0) atomicAdd(ssum, (double)s);
    } else {
        // ---- dense term (upper-triangle tiles, row-paired) ----
        int dbx  = bx - NSBLK;
        int wave = tid >> 6, lane = tid & 63;
        int g = lane >> 4, r = lane & 15;
        int p  = dbx >> 3;                       // row-pair index [0,256)
        int wv = (dbx & 7) * 4 + wave;           // wave within pair [0,32)
        int k0 = (wv * 513) / NWPP;
        int k1 = ((wv + 1) * 513) / NWPP;
        int n1 = NT - p;                         // tiles in row ti = p
        int boff = (g >> 1) * 8;                 // B k-group: g<2 -> hi, g>=2 -> lo

        float ax = 0.f, ay = 0.f, az = 0.f, aw = 0.f;

        // segment A: row ti = p, tj = p + k for k in [k0, min(k1,n1))
        int eA = k1 < n1 ? k1 : n1;
        if (k0 < eA) {
            int ti = p;
            short8_t afrag = *(const short8_t*)(zhl + (size_t)(ti * 16 + r) * 16 + (g & 1) * 8);
            float4 u4 = *(const float4*)(u + ti * 16 + g * 4);
            dense_sweep(zhl, v, afrag, u4, boff, ti, p + k0, eA - k0, r, ax, ay, az, aw);
        }
        // segment B: row ti = 511-p, tj = ti + (k - n1) for k in [max(k0,n1), k1)
        int sB = k0 > n1 ? k0 : n1;
        if (sB < k1) {
            int ti = (NT - 1) - p;
            short8_t afrag = *(const short8_t*)(zhl + (size_t)(ti * 16 + r) * 16 + (g & 1) * 8);
            float4 u4 = *(const float4*)(u + ti * 16 + g * 4);
            dense_sweep(zhl, v, afrag, u4, boff, ti, ti + (sB - n1), k1 - sB, r, ax, ay, az, aw);
        }
        float s = block_reduce_f((ax + ay) + (az + aw), red);
        if (tid == 0) atomicAdd(dsum, (double)s);
    }

    // ---- last arriving block composes the output ----
    if (tid == 0) {
        __threadfence();
        unsigned int old = atomicAdd(counter, 1u);
        if (old == NBLK - 1) {
            __threadfence();
            double Dsum = atomicAdd(dsum, 0.0);
            double Ssum = atomicAdd(ssum, 0.0);
            // diagonal entries are exp(-sqrt(8)*eps); subtract exactly
            double trace = (double)S * exp(-sqrt(8.0) * (double)EPSF);
            double offdiag = Dsum - trace;
            double a = (double)alpha[0];
            double z_pdist2 = (double)ne * a - Ssum;
            double z_pdist1 = exp(a) * 0.5 * 7.3890560989306495 * offdiag;
            out[0] = (float)(z_pdist2 - z_pdist1);
        }
    }
}

extern "C" void kernel_launch(void* const* d_in, const int* in_sizes, int n_in,
                              void* d_out, int out_size, void* d_ws, size_t ws_size,
                              hipStream_t stream) {
    const float* latent_Z = (const float*)d_in[0];
    const float* alpha    = (const float*)d_in[1];
    const int*   sidx     = (const int*)d_in[2];
    const int*   ei       = (const int*)d_in[3];
    const int*   ej       = (const int*)d_in[4];
    int ne = in_sizes[3];
    float* out = (float*)d_out;
    char*  ws  = (char*)d_ws;

    ushort* zhl   = (ushort*)(ws + ZHL_OFF);
    float*  u     = (float*)(ws + U_OFF);
    float*  v     = (float*)(ws + V_OFF);
    double* dsum  = (double*)(ws + ACC_OFF);
    double* ssum  = (double*)(ws + ACC_OFF + 8);
    unsigned int* counter = (unsigned int*)(ws + ACC_OFF + 16);

    gather_kernel<<<S / 256, 256, 0, stream>>>(latent_Z, sidx, zhl, u, v,
                                               dsum, ssum, counter);
    fused_kernel<<<NBLK, 256, 0, stream>>>(zhl, u, v, latent_Z, ei, ej, ne,
                                           alpha, dsum, ssum, counter, out);
}

// Round 9
// 55.436 us; speedup vs baseline: 1.4677x; 1.4677x over previous
//
#include <hip/hip_runtime.h>
#include <hip/hip_bf16.h>
#include <math.h>

#define S        8192
#define D        8
#define EPSF     1e-6f
#define LOG2E    1.442695040888963f
#define EPS_S    (LOG2E * EPSF)
#define NT       512        // 8192/16 tiles per dim

// ws byte offsets
#define ZHL_OFF  0          // 8192 rows x 16 ushort (hi[8]|lo[8]) = 262144 B
#define U_OFF    262144     // 8192 f32
#define V_OFF    294912     // 8192 f32
#define SP_OFF   327680     // 128 f32 sparse partials
#define ACC_OFF  328704     // double dsum, uint counter

#define NSBLK    128        // prep blocks (512 threads)
#define NDBLK    1024       // dense blocks = 256 row-pairs x 4 (512 threads)
#define NWPP     32         // waves per row-pair

typedef __attribute__((ext_vector_type(8))) short short8_t;
typedef __attribute__((ext_vector_type(4))) float f32x4;

__device__ __forceinline__ float block_reduce_f(float v, float* sm) {
    #pragma unroll
    for (int off = 32; off > 0; off >>= 1) v += __shfl_down(v, off, 64);
    int lane = threadIdx.x & 63, wid = threadIdx.x >> 6;
    if (lane == 0) sm[wid] = v;
    __syncthreads();
    float s = 0.f;
    if (threadIdx.x == 0) {
        int nw = blockDim.x >> 6;
        for (int w = 0; w < nw; ++w) s += sm[w];
    }
    return s;
}

// ---- kernel 1: gather+convert (64 rows/block) || sparse edge term ----
// Writes spart[] with plain stores (kernel-boundary flush makes them visible),
// zeroes dsum/counter (only k2 touches those -> no intra-node race).
__global__ __launch_bounds__(512) void prep_kernel(
        const float* __restrict__ Z, const int* __restrict__ sidx,
        const int* __restrict__ ei, const int* __restrict__ ej, int ne,
        ushort* __restrict__ zhl, float* __restrict__ u, float* __restrict__ v,
        float* __restrict__ spart, double* __restrict__ dsum,
        unsigned int* __restrict__ counter) {
    __shared__ float red[8];
    int tid = threadIdx.x, bx = blockIdx.x;

    if (bx == 0 && tid == 511) { *dsum = 0.0; *counter = 0u; }

    // gather prologue: rows bx*64 .. bx*64+63
    if (tid < 64) {
        int t = bx * 64 + tid;
        int n = sidx[t];
        const float4* zp = (const float4*)(Z + (size_t)n * D);
        float4 a = zp[0], b = zp[1];
        float z[8] = { a.x, a.y, a.z, a.w, b.x, b.y, b.z, b.w };
        float ss = 0.f;
        short8_t h, l;
        #pragma unroll
        for (int k = 0; k < 8; ++k) {
            float zs = LOG2E * z[k];
            ss = fmaf(zs, zs, ss);
            __hip_bfloat16 hb = __float2bfloat16(zs);
            float hf = __bfloat162float(hb);
            __hip_bfloat16 lb = __float2bfloat16(zs - hf);
            h[k] = (short)__builtin_bit_cast(unsigned short, hb);
            l[k] = (short)__builtin_bit_cast(unsigned short, lb);
        }
        *(short8_t*)(zhl + (size_t)t * 16)     = h;
        *(short8_t*)(zhl + (size_t)t * 16 + 8) = l;
        u[t] = ss + 8.f * EPS_S * EPS_S;
        v[t] = ss;
    }

    // sparse positive-edge term
    float acc = 0.f;
    int nchunk = ne >> 2;
    for (int c = bx * 512 + tid; c < nchunk; c += NSBLK * 512) {
        int4 ia = ((const int4*)ei)[c];
        int4 ib = ((const int4*)ej)[c];
        int aidx[4] = { ia.x, ia.y, ia.z, ia.w };
        int bidx[4] = { ib.x, ib.y, ib.z, ib.w };
        #pragma unroll
        for (int q = 0; q < 4; ++q) {
            const float4* za = (const float4*)(Z + (size_t)aidx[q] * D);
            const float4* zb = (const float4*)(Z + (size_t)bidx[q] * D);
            float4 a0 = za[0], a1 = za[1];
            float4 b0 = zb[0], b1 = zb[1];
            float d0 = a0.x - b0.x + EPSF;
            float d1 = a0.y - b0.y + EPSF;
            float d2 = a0.z - b0.z + EPSF;
            float d3 = a0.w - b0.w + EPSF;
            float d4 = a1.x - b1.x + EPSF;
            float d5 = a1.y - b1.y + EPSF;
            float d6 = a1.z - b1.z + EPSF;
            float d7 = a1.w - b1.w + EPSF;
            float s2 = d0 * d0;
            s2 = fmaf(d1, d1, s2);
            s2 = fmaf(d2, d2, s2);
            s2 = fmaf(d3, d3, s2);
            s2 = fmaf(d4, d4, s2);
            s2 = fmaf(d5, d5, s2);
            s2 = fmaf(d6, d6, s2);
            s2 = fmaf(d7, d7, s2);
            acc += __builtin_amdgcn_sqrtf(s2);
        }
    }
    for (int e = (nchunk << 2) + bx * 512 + tid; e < ne; e += NSBLK * 512) {
        int a = ei[e], b = ej[e];
        const float4* za = (const float4*)(Z + (size_t)a * D);
        const float4* zb = (const float4*)(Z + (size_t)b * D);
        float4 a0 = za[0], a1 = za[1];
        float4 b0 = zb[0], b1 = zb[1];
        float d0 = a0.x - b0.x + EPSF, d1 = a0.y - b0.y + EPSF;
        float d2 = a0.z - b0.z + EPSF, d3 = a0.w - b0.w + EPSF;
        float d4 = a1.x - b1.x + EPSF, d5 = a1.y - b1.y + EPSF;
        float d6 = a1.z - b1.z + EPSF, d7 = a1.w - b1.w + EPSF;
        float s2 = d0 * d0;
        s2 = fmaf(d1, d1, s2); s2 = fmaf(d2, d2, s2); s2 = fmaf(d3, d3, s2);
        s2 = fmaf(d4, d4, s2); s2 = fmaf(d5, d5, s2); s2 = fmaf(d6, d6, s2);
        s2 = fmaf(d7, d7, s2);
        acc += __builtin_amdgcn_sqrtf(s2);
    }
    float s = block_reduce_f(acc, red);
    if (tid == 0) spart[bx] = s;
}

// Sweep `cnt` consecutive j-tiles starting at tj0 for fixed i-tile ti.
// Off-diagonal tiles weight 2 (mirror not enumerated), diagonal tile weight 1.
// Depth-1 register prefetch (r5-proven form).
__device__ __forceinline__ void dense_sweep(const ushort* __restrict__ zhl,
                                            const float* __restrict__ v,
                                            short8_t afrag, float4 u4, int boff,
                                            int ti, int tj0, int cnt, int r,
                                            float& ax, float& ay, float& az, float& aw) {
    const ushort* bp = zhl + (size_t)(tj0 * 16 + r) * 16 + boff;
    const float*  vp = v + tj0 * 16 + r;
    short8_t bnext = *(const short8_t*)bp;
    float    vnext = vp[0];
    #pragma unroll 4
    for (int t = 0; t < cnt; ++t) {
        short8_t bcur = bnext;
        float    vcur = vnext;
        if (t + 1 < cnt) {
            bnext = *(const short8_t*)(bp + (size_t)(t + 1) * 256);
            vnext = vp[(t + 1) * 16];
        }
        float w = (tj0 + t == ti) ? 1.f : 2.f;
        f32x4 c = { 0.f, 0.f, 0.f, 0.f };
        c = __builtin_amdgcn_mfma_f32_16x16x32_bf16(afrag, bcur, c, 0, 0, 0);
        float d2_0 = fmaf(c[0], -2.f, u4.x + vcur);
        float d2_1 = fmaf(c[1], -2.f, u4.y + vcur);
        float d2_2 = fmaf(c[2], -2.f, u4.z + vcur);
        float d2_3 = fmaf(c[3], -2.f, u4.w + vcur);
        ax = fmaf(w, __builtin_amdgcn_exp2f(-__builtin_amdgcn_sqrtf(__builtin_fabsf(d2_0))), ax);
        ay = fmaf(w, __builtin_amdgcn_exp2f(-__builtin_amdgcn_sqrtf(__builtin_fabsf(d2_1))), ay);
        az = fmaf(w, __builtin_amdgcn_exp2f(-__builtin_amdgcn_sqrtf(__builtin_fabsf(d2_2))), az);
        aw = fmaf(w, __builtin_amdgcn_exp2f(-__builtin_amdgcn_sqrtf(__builtin_fabsf(d2_3))), aw);
    }
}

// ---- kernel 2: dense triangle; atomic-only finalize (NO threadfence) ----
__global__ __launch_bounds__(512) void dense_kernel(
        const ushort* __restrict__ zhl, const float* __restrict__ u,
        const float* __restrict__ v, const float* __restrict__ alpha,
        const float* __restrict__ spart, double* __restrict__ dsum,
        unsigned int* __restrict__ counter, float* __restrict__ out, int ne) {
    __shared__ float red[8];
    __shared__ int amLast;
    int tid = threadIdx.x, bx = blockIdx.x;
    int wave = tid >> 6, lane = tid & 63;
    int g = lane >> 4, r = lane & 15;
    int p  = bx >> 2;                      // row-pair index [0,256)
    int wv = (bx & 3) * 8 + wave;          // wave within pair [0,32)
    int k0 = (wv * 513) / NWPP;
    int k1 = ((wv + 1) * 513) / NWPP;
    int n1 = NT - p;                       // tiles in row ti = p
    int boff = (g >> 1) * 8;               // B k-group: g<2 -> hi, g>=2 -> lo

    float ax = 0.f, ay = 0.f, az = 0.f, aw = 0.f;

    // segment A: row ti = p, tj = p + k for k in [k0, min(k1,n1))
    int eA = k1 < n1 ? k1 : n1;
    if (k0 < eA) {
        int ti = p;
        short8_t afrag = *(const short8_t*)(zhl + (size_t)(ti * 16 + r) * 16 + (g & 1) * 8);
        float4 u4 = *(const float4*)(u + ti * 16 + g * 4);
        dense_sweep(zhl, v, afrag, u4, boff, ti, p + k0, eA - k0, r, ax, ay, az, aw);
    }
    // segment B: row ti = 511-p, tj = ti + (k - n1) for k in [max(k0,n1), k1)
    int sB = k0 > n1 ? k0 : n1;
    if (sB < k1) {
        int ti = (NT - 1) - p;
        short8_t afrag = *(const short8_t*)(zhl + (size_t)(ti * 16 + r) * 16 + (g & 1) * 8);
        float4 u4 = *(const float4*)(u + ti * 16 + g * 4);
        dense_sweep(zhl, v, afrag, u4, boff, ti, ti + (sB - n1), k1 - sB, r, ax, ay, az, aw);
    }
    float s = block_reduce_f((ax + ay) + (az + aw), red);

    if (tid == 0) {
        // device-scope atomic: coherent at the common point, no fence needed
        double old = atomicAdd(dsum, (double)s);
        __builtin_amdgcn_s_waitcnt(0);               // dsum add completed
        unsigned inc = 1u | (unsigned)(old == 1.0e300);  // data-dep ordering
        unsigned cnt = atomicAdd(counter, inc);
        amLast = (cnt == NDBLK - 1) ? 1 : 0;
    }
    __syncthreads();

    if (amLast && tid < 64) {
        // wave 0 of the last block: reduce sparse partials + compose
        double ss = (double)spart[tid] + (double)spart[tid + 64];
        #pragma unroll
        for (int off = 32; off > 0; off >>= 1) ss += __shfl_down(ss, off, 64);
        if (tid == 0) {
            double Dsum = atomicAdd(dsum, 0.0);      // atomic read at coherence point
            double Ssum = ss;
            // diagonal entries are exp(-sqrt(8)*eps); subtract exactly
            double trace = (double)S * exp(-sqrt(8.0) * (double)EPSF);
            double offdiag = Dsum - trace;
            double a = (double)alpha[0];
            double z_pdist2 = (double)ne * a - Ssum;
            double z_pdist1 = exp(a) * 0.5 * 7.3890560989306495 * offdiag;
            out[0] = (float)(z_pdist2 - z_pdist1);
        }
    }
}

extern "C" void kernel_launch(void* const* d_in, const int* in_sizes, int n_in,
                              void* d_out, int out_size, void* d_ws, size_t ws_size,
                              hipStream_t stream) {
    const float* latent_Z = (const float*)d_in[0];
    const float* alpha    = (const float*)d_in[1];
    const int*   sidx     = (const int*)d_in[2];
    const int*   ei       = (const int*)d_in[3];
    const int*   ej       = (const int*)d_in[4];
    int ne = in_sizes[3];
    float* out = (float*)d_out;
    char*  ws  = (char*)d_ws;

    ushort* zhl   = (ushort*)(ws + ZHL_OFF);
    float*  u     = (float*)(ws + U_OFF);
    float*  v     = (float*)(ws + V_OFF);
    float*  spart = (float*)(ws + SP_OFF);
    double* dsum  = (double*)(ws + ACC_OFF);
    unsigned int* counter = (unsigned int*)(ws + ACC_OFF + 8);

    prep_kernel<<<NSBLK, 512, 0, stream>>>(latent_Z, sidx, ei, ej, ne,
                                           zhl, u, v, spart, dsum, counter);
    dense_kernel<<<NDBLK, 512, 0, stream>>>(zhl, u, v, alpha, spart,
                                            dsum, counter, out, ne);
}

// Round 10
// 33.760 us; speedup vs baseline: 2.4100x; 1.6421x over previous
//
#include <hip/hip_runtime.h>
#include <hip/hip_bf16.h>
#include <math.h>

#define NNODES   100000
#define S        8192
#define D        8
#define EPSF     1e-6f
#define LOG2E    1.442695040888963f
#define EPS_S    (LOG2E * EPSF)
#define NT       512        // 8192/16 tiles per dim

// ws byte offsets
#define ZHL_OFF  0          // 8192 rows x 16 ushort (hi[8]|lo[8]) = 262144 B
#define U_OFF    262144     // 8192 f32
#define V_OFF    294912     // 8192 f32
#define DP_OFF   327680     // 1792 f32 dense partials
#define SP_OFF   334848     // 256 f32 sparse partials
#define ZB_OFF   335872     // 100000 rows x 8 bf16 = 1.6 MB

#define NSBLK    256        // sparse blocks
#define NDBLK    1792       // dense blocks = 256 row-pairs x 7
#define NWPP     28         // waves per row-pair

typedef __attribute__((ext_vector_type(8))) short short8_t;
typedef __attribute__((ext_vector_type(4))) float f32x4;

__device__ __forceinline__ float block_reduce_f(float v, float* sm) {
    #pragma unroll
    for (int off = 32; off > 0; off >>= 1) v += __shfl_down(v, off, 64);
    int lane = threadIdx.x & 63, wid = threadIdx.x >> 6;
    if (lane == 0) sm[wid] = v;
    __syncthreads();
    float s = 0.f;
    if (threadIdx.x == 0) {
        for (int w = 0; w < 4; ++w) s += sm[w];
    }
    return s;
}

// ---- kernel 1: sample-gather (prescaled hi/lo split) + full-Z bf16 copy ----
__global__ __launch_bounds__(256) void gather_kernel(const float* __restrict__ Z,
                                                     const int* __restrict__ idx,
                                                     ushort* __restrict__ zhl,
                                                     float* __restrict__ u,
                                                     float* __restrict__ v,
                                                     ushort* __restrict__ zb16) {
    int gid = blockIdx.x * 256 + threadIdx.x;

    if (gid < S) {
        int n = idx[gid];
        const float4* zp = (const float4*)(Z + (size_t)n * D);
        float4 a = zp[0], b = zp[1];
        float z[8] = { a.x, a.y, a.z, a.w, b.x, b.y, b.z, b.w };
        float ss = 0.f;
        short8_t h, l;
        #pragma unroll
        for (int k = 0; k < 8; ++k) {
            float zs = LOG2E * z[k];
            ss = fmaf(zs, zs, ss);
            __hip_bfloat16 hb = __float2bfloat16(zs);
            float hf = __bfloat162float(hb);
            __hip_bfloat16 lb = __float2bfloat16(zs - hf);
            h[k] = (short)__builtin_bit_cast(unsigned short, hb);
            l[k] = (short)__builtin_bit_cast(unsigned short, lb);
        }
        *(short8_t*)(zhl + (size_t)gid * 16)     = h;
        *(short8_t*)(zhl + (size_t)gid * 16 + 8) = l;
        u[gid] = ss + 8.f * EPS_S * EPS_S;
        v[gid] = ss;
    }

    if (gid < NNODES) {
        const float4* zp = (const float4*)(Z + (size_t)gid * D);
        float4 a = zp[0], b = zp[1];
        float z[8] = { a.x, a.y, a.z, a.w, b.x, b.y, b.z, b.w };
        short8_t o;
        #pragma unroll
        for (int k = 0; k < 8; ++k) {
            __hip_bfloat16 bb = __float2bfloat16(z[k]);
            o[k] = (short)__builtin_bit_cast(unsigned short, bb);
        }
        *(short8_t*)(zb16 + (size_t)gid * 8) = o;
    }
}

// bf16 row (uint4) -> 8 f32
#define UNPACK8(u4, f)                                        \
    f[0] = __uint_as_float(u4.x << 16);                       \
    f[1] = __uint_as_float(u4.x & 0xffff0000u);               \
    f[2] = __uint_as_float(u4.y << 16);                       \
    f[3] = __uint_as_float(u4.y & 0xffff0000u);               \
    f[4] = __uint_as_float(u4.z << 16);                       \
    f[5] = __uint_as_float(u4.z & 0xffff0000u);               \
    f[6] = __uint_as_float(u4.w << 16);                       \
    f[7] = __uint_as_float(u4.w & 0xffff0000u);

__device__ __forceinline__ float edge_dist4(const uint4* __restrict__ zb,
                                            int4 ia, int4 ib) {
    float acc = 0.f;
    int aidx[4] = { ia.x, ia.y, ia.z, ia.w };
    int bidx[4] = { ib.x, ib.y, ib.z, ib.w };
    #pragma unroll
    for (int q = 0; q < 4; ++q) {
        uint4 ua = zb[aidx[q]];
        uint4 ub = zb[bidx[q]];
        float fa[8], fb[8];
        UNPACK8(ua, fa);
        UNPACK8(ub, fb);
        float s2 = 0.f;
        #pragma unroll
        for (int k = 0; k < 8; ++k) {
            float d = fa[k] - fb[k] + EPSF;
            s2 = fmaf(d, d, s2);
        }
        acc += __builtin_amdgcn_sqrtf(s2);
    }
    return acc;
}

// Sweep `cnt` consecutive j-tiles starting at tj0 for fixed i-tile ti.
// Off-diagonal tiles weight 2 (mirror not enumerated), diagonal tile weight 1.
__device__ __forceinline__ void dense_sweep(const ushort* __restrict__ zhl,
                                            const float* __restrict__ v,
                                            short8_t afrag, float4 u4, int boff,
                                            int ti, int tj0, int cnt, int r,
                                            float& ax, float& ay, float& az, float& aw) {
    const ushort* bp = zhl + (size_t)(tj0 * 16 + r) * 16 + boff;
    const float*  vp = v + tj0 * 16 + r;
    short8_t bnext = *(const short8_t*)bp;
    float    vnext = vp[0];
    #pragma unroll 4
    for (int t = 0; t < cnt; ++t) {
        short8_t bcur = bnext;
        float    vcur = vnext;
        if (t + 1 < cnt) {
            bnext = *(const short8_t*)(bp + (size_t)(t + 1) * 256);
            vnext = vp[(t + 1) * 16];
        }
        float w = (tj0 + t == ti) ? 1.f : 2.f;
        f32x4 c = { 0.f, 0.f, 0.f, 0.f };
        c = __builtin_amdgcn_mfma_f32_16x16x32_bf16(afrag, bcur, c, 0, 0, 0);
        float d2_0 = fmaf(c[0], -2.f, u4.x + vcur);
        float d2_1 = fmaf(c[1], -2.f, u4.y + vcur);
        float d2_2 = fmaf(c[2], -2.f, u4.z + vcur);
        float d2_3 = fmaf(c[3], -2.f, u4.w + vcur);
        ax = fmaf(w, __builtin_amdgcn_exp2f(-__builtin_amdgcn_sqrtf(__builtin_fabsf(d2_0))), ax);
        ay = fmaf(w, __builtin_amdgcn_exp2f(-__builtin_amdgcn_sqrtf(__builtin_fabsf(d2_1))), ay);
        az = fmaf(w, __builtin_amdgcn_exp2f(-__builtin_amdgcn_sqrtf(__builtin_fabsf(d2_2))), az);
        aw = fmaf(w, __builtin_amdgcn_exp2f(-__builtin_amdgcn_sqrtf(__builtin_fabsf(d2_3))), aw);
    }
}

// ---- kernel 2: sparse (blocks < NSBLK) || dense triangle (rest) ----
__global__ __launch_bounds__(256) void fused_kernel(
        const ushort* __restrict__ zhl, const float* __restrict__ u,
        const float* __restrict__ v, const ushort* __restrict__ zb16,
        const int* __restrict__ ei, const int* __restrict__ ej, int ne,
        float* __restrict__ dpart, float* __restrict__ spart) {
    __shared__ float red[4];
    int tid = threadIdx.x, bx = blockIdx.x;

    if (bx < NSBLK) {
        // ---- sparse positive-edge term (bf16 rows, idx-prefetched) ----
        const uint4* zb = (const uint4*)zb16;
        float acc = 0.f;
        int nchunk = ne >> 2;
        int stride = NSBLK * 256;
        int c = bx * 256 + tid;
        if (c < nchunk) {
            int4 ia = ((const int4*)ei)[c];
            int4 ib = ((const int4*)ej)[c];
            while (true) {
                int cn = c + stride;
                int4 ian, ibn;
                bool more = cn < nchunk;
                if (more) {
                    ian = ((const int4*)ei)[cn];
                    ibn = ((const int4*)ej)[cn];
                }
                acc += edge_dist4(zb, ia, ib);
                if (!more) break;
                ia = ian; ib = ibn; c = cn;
            }
        }
        // tail (ne % 4)
        for (int e = (nchunk << 2) + bx * 256 + tid; e < ne; e += stride) {
            uint4 ua = zb[ei[e]];
            uint4 ub = zb[ej[e]];
            float fa[8], fb[8];
            UNPACK8(ua, fa);
            UNPACK8(ub, fb);
            float s2 = 0.f;
            #pragma unroll
            for (int k = 0; k < 8; ++k) {
                float d = fa[k] - fb[k] + EPSF;
                s2 = fmaf(d, d, s2);
            }
            acc += __builtin_amdgcn_sqrtf(s2);
        }
        float s = block_reduce_f(acc, red);
        if (tid == 0) spart[bx] = s;
        return;
    }

    // ---- dense term (upper-triangle tiles, row-paired) ----
    int dbx  = bx - NSBLK;
    int wave = tid >> 6, lane = tid & 63;
    int g = lane >> 4, r = lane & 15;
    int p  = dbx / 7;                        // row-pair index [0,256)
    int wv = (dbx - p * 7) * 4 + wave;       // wave within pair [0,28)
    int k0 = (wv * 513) / NWPP;
    int k1 = ((wv + 1) * 513) / NWPP;
    int n1 = NT - p;                         // tiles in row ti = p
    int boff = (g >> 1) * 8;                 // B k-group: g<2 -> hi, g>=2 -> lo

    float ax = 0.f, ay = 0.f, az = 0.f, aw = 0.f;

    // segment A: row ti = p, tj = p + k for k in [k0, min(k1,n1))
    int eA = k1 < n1 ? k1 : n1;
    if (k0 < eA) {
        int ti = p;
        short8_t afrag = *(const short8_t*)(zhl + (size_t)(ti * 16 + r) * 16 + (g & 1) * 8);
        float4 u4 = *(const float4*)(u + ti * 16 + g * 4);
        dense_sweep(zhl, v, afrag, u4, boff, ti, p + k0, eA - k0, r, ax, ay, az, aw);
    }
    // segment B: row ti = 511-p, tj = ti + (k - n1) for k in [max(k0,n1), k1)
    int sB = k0 > n1 ? k0 : n1;
    if (sB < k1) {
        int ti = (NT - 1) - p;
        short8_t afrag = *(const short8_t*)(zhl + (size_t)(ti * 16 + r) * 16 + (g & 1) * 8);
        float4 u4 = *(const float4*)(u + ti * 16 + g * 4);
        dense_sweep(zhl, v, afrag, u4, boff, ti, ti + (sB - n1), k1 - sB, r, ax, ay, az, aw);
    }
    float s = block_reduce_f((ax + ay) + (az + aw), red);
    if (tid == 0) dpart[dbx] = s;
}

// ---- kernel 3: double-precision reduce of partials, compose scalar ----
__global__ __launch_bounds__(256) void final_kernel(const float* __restrict__ alpha,
                                                    const float* __restrict__ dpart,
                                                    const float* __restrict__ spart,
                                                    float* __restrict__ out,
                                                    int ne) {
    __shared__ double rd[4], rs[4];
    double ds = 0.0, ss = 0.0;
    for (int k = threadIdx.x; k < NDBLK; k += 256) ds += (double)dpart[k];
    for (int k = threadIdx.x; k < NSBLK; k += 256) ss += (double)spart[k];
    #pragma unroll
    for (int off = 32; off > 0; off >>= 1) {
        ds += __shfl_down(ds, off, 64);
        ss += __shfl_down(ss, off, 64);
    }
    int lane = threadIdx.x & 63, wid = threadIdx.x >> 6;
    if (lane == 0) { rd[wid] = ds; rs[wid] = ss; }
    __syncthreads();
    if (threadIdx.x == 0) {
        double Dsum = 0.0, Ssum = 0.0;
        for (int w = 0; w < 4; ++w) { Dsum += rd[w]; Ssum += rs[w]; }
        // diagonal entries are exp(-sqrt(8)*eps); subtract exactly
        double trace = (double)S * exp(-sqrt(8.0) * (double)EPSF);
        double offdiag = Dsum - trace;
        double a = (double)alpha[0];
        double z_pdist2 = (double)ne * a - Ssum;
        double z_pdist1 = exp(a) * 0.5 * 7.3890560989306495 * offdiag;
        out[0] = (float)(z_pdist2 - z_pdist1);
    }
}

extern "C" void kernel_launch(void* const* d_in, const int* in_sizes, int n_in,
                              void* d_out, int out_size, void* d_ws, size_t ws_size,
                              hipStream_t stream) {
    const float* latent_Z = (const float*)d_in[0];
    const float* alpha    = (const float*)d_in[1];
    const int*   sidx     = (const int*)d_in[2];
    const int*   ei       = (const int*)d_in[3];
    const int*   ej       = (const int*)d_in[4];
    int ne = in_sizes[3];
    float* out = (float*)d_out;
    char*  ws  = (char*)d_ws;

    ushort* zhl   = (ushort*)(ws + ZHL_OFF);
    float*  u     = (float*)(ws + U_OFF);
    float*  v     = (float*)(ws + V_OFF);
    float*  dpart = (float*)(ws + DP_OFF);
    float*  spart = (float*)(ws + SP_OFF);
    ushort* zb16  = (ushort*)(ws + ZB_OFF);

    gather_kernel<<<(NNODES + 255) / 256, 256, 0, stream>>>(latent_Z, sidx,
                                                            zhl, u, v, zb16);
    fused_kernel<<<NSBLK + NDBLK, 256, 0, stream>>>(zhl, u, v, zb16, ei, ej, ne,
                                                    dpart, spart);
    final_kernel<<<1, 256, 0, stream>>>(alpha, dpart, spart, out, ne);
}

// Round 11
// 30.211 us; speedup vs baseline: 2.6931x; 1.1175x over previous
//
#include <hip/hip_runtime.h>
#include <hip/hip_bf16.h>
#include <math.h>

#define NNODES   100000
#define S        8192
#define D        8
#define EPSF     1e-6f
#define LOG2E    1.442695040888963f
#define EPS_S    (LOG2E * EPSF)
#define NT2      256        // 8192/32 tiles per dim

// ws byte offsets
#define ZHL_OFF  0          // 8192 rows x 16 ushort (hi[8]|lo[8]) = 262144 B
#define U_OFF    262144     // 8192 f32
#define V_OFF    294912     // 8192 f32
#define DP_OFF   327680     // 1024 f32 dense partials
#define SP_OFF   331776     // 256 f32 sparse partials
#define ZB_OFF   332800     // 100000 rows x 8 bf16 = 1.6 MB

#define NSBLK    256        // sparse blocks
#define NDBLK    1024       // dense blocks = 128 row-pairs x 8
#define NWPP     32         // waves per row-pair

typedef __attribute__((ext_vector_type(8)))  short short8_t;
typedef __attribute__((ext_vector_type(16))) float f32x16;

__device__ __forceinline__ float block_reduce_f(float v, float* sm) {
    #pragma unroll
    for (int off = 32; off > 0; off >>= 1) v += __shfl_down(v, off, 64);
    int lane = threadIdx.x & 63, wid = threadIdx.x >> 6;
    if (lane == 0) sm[wid] = v;
    __syncthreads();
    float s = 0.f;
    if (threadIdx.x == 0) {
        for (int w = 0; w < 4; ++w) s += sm[w];
    }
    return s;
}

// ---- kernel 1: sample-gather (prescaled hi/lo split) + full-Z bf16 copy ----
__global__ __launch_bounds__(256) void gather_kernel(const float* __restrict__ Z,
                                                     const int* __restrict__ idx,
                                                     ushort* __restrict__ zhl,
                                                     float* __restrict__ u,
                                                     float* __restrict__ v,
                                                     ushort* __restrict__ zb16) {
    int gid = blockIdx.x * 256 + threadIdx.x;

    if (gid < S) {
        int n = idx[gid];
        const float4* zp = (const float4*)(Z + (size_t)n * D);
        float4 a = zp[0], b = zp[1];
        float z[8] = { a.x, a.y, a.z, a.w, b.x, b.y, b.z, b.w };
        float ss = 0.f;
        short8_t h, l;
        #pragma unroll
        for (int k = 0; k < 8; ++k) {
            float zs = LOG2E * z[k];
            ss = fmaf(zs, zs, ss);
            __hip_bfloat16 hb = __float2bfloat16(zs);
            float hf = __bfloat162float(hb);
            __hip_bfloat16 lb = __float2bfloat16(zs - hf);
            h[k] = (short)__builtin_bit_cast(unsigned short, hb);
            l[k] = (short)__builtin_bit_cast(unsigned short, lb);
        }
        *(short8_t*)(zhl + (size_t)gid * 16)     = h;
        *(short8_t*)(zhl + (size_t)gid * 16 + 8) = l;
        u[gid] = ss + 8.f * EPS_S * EPS_S;
        v[gid] = ss;
    }

    if (gid < NNODES) {
        const float4* zp = (const float4*)(Z + (size_t)gid * D);
        float4 a = zp[0], b = zp[1];
        float z[8] = { a.x, a.y, a.z, a.w, b.x, b.y, b.z, b.w };
        short8_t o;
        #pragma unroll
        for (int k = 0; k < 8; ++k) {
            __hip_bfloat16 bb = __float2bfloat16(z[k]);
            o[k] = (short)__builtin_bit_cast(unsigned short, bb);
        }
        *(short8_t*)(zb16 + (size_t)gid * 8) = o;
    }
}

// bf16 row (uint4) -> 8 f32
#define UNPACK8(u4, f)                                        \
    f[0] = __uint_as_float(u4.x << 16);                       \
    f[1] = __uint_as_float(u4.x & 0xffff0000u);               \
    f[2] = __uint_as_float(u4.y << 16);                       \
    f[3] = __uint_as_float(u4.y & 0xffff0000u);               \
    f[4] = __uint_as_float(u4.z << 16);                       \
    f[5] = __uint_as_float(u4.z & 0xffff0000u);               \
    f[6] = __uint_as_float(u4.w << 16);                       \
    f[7] = __uint_as_float(u4.w & 0xffff0000u);

__device__ __forceinline__ float edge_dist4(const uint4* __restrict__ zb,
                                            int4 ia, int4 ib) {
    float acc = 0.f;
    int aidx[4] = { ia.x, ia.y, ia.z, ia.w };
    int bidx[4] = { ib.x, ib.y, ib.z, ib.w };
    #pragma unroll
    for (int q = 0; q < 4; ++q) {
        uint4 ua = zb[aidx[q]];
        uint4 ub = zb[bidx[q]];
        float fa[8], fb[8];
        UNPACK8(ua, fa);
        UNPACK8(ub, fb);
        float s2 = 0.f;
        #pragma unroll
        for (int k = 0; k < 8; ++k) {
            float d = fa[k] - fb[k] + EPSF;
            s2 = fmaf(d, d, s2);
        }
        acc += __builtin_amdgcn_sqrtf(s2);
    }
    return acc;
}

// Sweep `cnt` consecutive 32x32 j-tiles starting at tj0 for fixed i-tile ti.
// Hi/lo exact product via 2 chained MFMAs:
//   mfma(A=[hi|lo], B=[hi|hi]) -> hi.hi + lo.hi
//   mfma(A=[hi|lo], B=[lo|lo]) -> hi.lo + lo.lo  (accumulated)
// C/D: col = lane&31, row = (reg&3) + 8*(reg>>2) + 4*(lane>>5).
__device__ __forceinline__ void dense_sweep32(const ushort* __restrict__ zhl,
                                              const float* __restrict__ v,
                                              short8_t afrag, const float4* u4,
                                              int ti, int tj0, int cnt, int c31,
                                              float& ax, float& ay, float& az, float& aw) {
    const ushort* bp = zhl + (size_t)(tj0 * 32 + c31) * 16;
    const float*  vp = v + tj0 * 32 + c31;
    short8_t bh = *(const short8_t*)bp;
    short8_t bl = *(const short8_t*)(bp + 8);
    float    vt = vp[0];
    #pragma unroll 2
    for (int t = 0; t < cnt; ++t) {
        short8_t bhc = bh, blc = bl;
        float    vtc = vt;
        if (t + 1 < cnt) {
            bh = *(const short8_t*)(bp + (size_t)(t + 1) * 512);
            bl = *(const short8_t*)(bp + (size_t)(t + 1) * 512 + 8);
            vt = vp[(t + 1) * 32];
        }
        float w = (tj0 + t == ti) ? 1.f : 2.f;
        f32x16 c = { 0.f, 0.f, 0.f, 0.f, 0.f, 0.f, 0.f, 0.f,
                     0.f, 0.f, 0.f, 0.f, 0.f, 0.f, 0.f, 0.f };
        c = __builtin_amdgcn_mfma_f32_32x32x16_bf16(afrag, bhc, c, 0, 0, 0);
        c = __builtin_amdgcn_mfma_f32_32x32x16_bf16(afrag, blc, c, 0, 0, 0);
        #pragma unroll
        for (int q = 0; q < 4; ++q) {
            float s0 = u4[q].x + vtc, s1 = u4[q].y + vtc;
            float s2 = u4[q].z + vtc, s3 = u4[q].w + vtc;
            float d0 = fmaf(c[4*q+0], -2.f, s0);
            float d1 = fmaf(c[4*q+1], -2.f, s1);
            float d2 = fmaf(c[4*q+2], -2.f, s2);
            float d3 = fmaf(c[4*q+3], -2.f, s3);
            ax = fmaf(w, __builtin_amdgcn_exp2f(-__builtin_amdgcn_sqrtf(__builtin_fabsf(d0))), ax);
            ay = fmaf(w, __builtin_amdgcn_exp2f(-__builtin_amdgcn_sqrtf(__builtin_fabsf(d1))), ay);
            az = fmaf(w, __builtin_amdgcn_exp2f(-__builtin_amdgcn_sqrtf(__builtin_fabsf(d2))), az);
            aw = fmaf(w, __builtin_amdgcn_exp2f(-__builtin_amdgcn_sqrtf(__builtin_fabsf(d3))), aw);
        }
    }
}

// ---- kernel 2: sparse (blocks < NSBLK) || dense 32x32 triangle (rest) ----
__global__ __launch_bounds__(256) void fused_kernel(
        const ushort* __restrict__ zhl, const float* __restrict__ u,
        const float* __restrict__ v, const ushort* __restrict__ zb16,
        const int* __restrict__ ei, const int* __restrict__ ej, int ne,
        float* __restrict__ dpart, float* __restrict__ spart) {
    __shared__ float red[4];
    int tid = threadIdx.x, bx = blockIdx.x;

    if (bx < NSBLK) {
        // ---- sparse positive-edge term (bf16 rows, idx-prefetched) ----
        const uint4* zb = (const uint4*)zb16;
        float acc = 0.f;
        int nchunk = ne >> 2;
        int stride = NSBLK * 256;
        int c = bx * 256 + tid;
        if (c < nchunk) {
            int4 ia = ((const int4*)ei)[c];
            int4 ib = ((const int4*)ej)[c];
            while (true) {
                int cn = c + stride;
                int4 ian, ibn;
                bool more = cn < nchunk;
                if (more) {
                    ian = ((const int4*)ei)[cn];
                    ibn = ((const int4*)ej)[cn];
                }
                acc += edge_dist4(zb, ia, ib);
                if (!more) break;
                ia = ian; ib = ibn; c = cn;
            }
        }
        for (int e = (nchunk << 2) + bx * 256 + tid; e < ne; e += stride) {
            uint4 ua = zb[ei[e]];
            uint4 ub = zb[ej[e]];
            float fa[8], fb[8];
            UNPACK8(ua, fa);
            UNPACK8(ub, fb);
            float s2 = 0.f;
            #pragma unroll
            for (int k = 0; k < 8; ++k) {
                float d = fa[k] - fb[k] + EPSF;
                s2 = fmaf(d, d, s2);
            }
            acc += __builtin_amdgcn_sqrtf(s2);
        }
        float s = block_reduce_f(acc, red);
        if (tid == 0) spart[bx] = s;
        return;
    }

    // ---- dense term (upper-triangle 32x32 tiles, row-paired) ----
    int dbx  = bx - NSBLK;
    int wave = tid >> 6, lane = tid & 63;
    int g = lane >> 5, c31 = lane & 31;

    int p  = dbx >> 3;                       // row-pair index [0,128)
    int wv = (dbx & 7) * 4 + wave;           // wave within pair [0,32)
    int k0 = (wv * 257) / NWPP;
    int k1 = ((wv + 1) * 257) / NWPP;
    int n1 = NT2 - p;                        // tiles in row ti = p

    float ax = 0.f, ay = 0.f, az = 0.f, aw = 0.f;

    // segment A: row ti = p, tj = p + k for k in [k0, min(k1,n1))
    int eA = k1 < n1 ? k1 : n1;
    if (k0 < eA) {
        int ti = p;
        // A frag: row ti*32 + c31; k-group 0 -> hi, 1 -> lo
        short8_t afrag = *(const short8_t*)(zhl + (size_t)(ti * 32 + c31) * 16 + g * 8);
        float4 u4[4];
        #pragma unroll
        for (int q = 0; q < 4; ++q) u4[q] = *(const float4*)(u + ti * 32 + 8 * q + 4 * g);
        dense_sweep32(zhl, v, afrag, u4, ti, p + k0, eA - k0, c31, ax, ay, az, aw);
    }
    // segment B: row ti = 255-p, tj = ti + (k - n1) for k in [max(k0,n1), k1)
    int sB = k0 > n1 ? k0 : n1;
    if (sB < k1) {
        int ti = (NT2 - 1) - p;
        short8_t afrag = *(const short8_t*)(zhl + (size_t)(ti * 32 + c31) * 16 + g * 8);
        float4 u4[4];
        #pragma unroll
        for (int q = 0; q < 4; ++q) u4[q] = *(const float4*)(u + ti * 32 + 8 * q + 4 * g);
        dense_sweep32(zhl, v, afrag, u4, ti, ti + (sB - n1), k1 - sB, c31, ax, ay, az, aw);
    }
    float s = block_reduce_f((ax + ay) + (az + aw), red);
    if (tid == 0) dpart[dbx] = s;
}

// ---- kernel 3: double-precision reduce of partials, compose scalar ----
__global__ __launch_bounds__(256) void final_kernel(const float* __restrict__ alpha,
                                                    const float* __restrict__ dpart,
                                                    const float* __restrict__ spart,
                                                    float* __restrict__ out,
                                                    int ne) {
    __shared__ double rd[4], rs[4];
    double ds = 0.0, ss = 0.0;
    for (int k = threadIdx.x; k < NDBLK; k += 256) ds += (double)dpart[k];
    for (int k = threadIdx.x; k < NSBLK; k += 256) ss += (double)spart[k];
    #pragma unroll
    for (int off = 32; off > 0; off >>= 1) {
        ds += __shfl_down(ds, off, 64);
        ss += __shfl_down(ss, off, 64);
    }
    int lane = threadIdx.x & 63, wid = threadIdx.x >> 6;
    if (lane == 0) { rd[wid] = ds; rs[wid] = ss; }
    __syncthreads();
    if (threadIdx.x == 0) {
        double Dsum = 0.0, Ssum = 0.0;
        for (int w = 0; w < 4; ++w) { Dsum += rd[w]; Ssum += rs[w]; }
        // diagonal entries are exp(-sqrt(8)*eps); subtract exactly
        double trace = (double)S * exp(-sqrt(8.0) * (double)EPSF);
        double offdiag = Dsum - trace;
        double a = (double)alpha[0];
        double z_pdist2 = (double)ne * a - Ssum;
        double z_pdist1 = exp(a) * 0.5 * 7.3890560989306495 * offdiag;
        out[0] = (float)(z_pdist2 - z_pdist1);
    }
}

extern "C" void kernel_launch(void* const* d_in, const int* in_sizes, int n_in,
                              void* d_out, int out_size, void* d_ws, size_t ws_size,
                              hipStream_t stream) {
    const float* latent_Z = (const float*)d_in[0];
    const float* alpha    = (const float*)d_in[1];
    const int*   sidx     = (const int*)d_in[2];
    const int*   ei       = (const int*)d_in[3];
    const int*   ej       = (const int*)d_in[4];
    int ne = in_sizes[3];
    float* out = (float*)d_out;
    char*  ws  = (char*)d_ws;

    ushort* zhl   = (ushort*)(ws + ZHL_OFF);
    float*  u     = (float*)(ws + U_OFF);
    float*  v     = (float*)(ws + V_OFF);
    float*  dpart = (float*)(ws + DP_OFF);
    float*  spart = (float*)(ws + SP_OFF);
    ushort* zb16  = (ushort*)(ws + ZB_OFF);

    gather_kernel<<<(NNODES + 255) / 256, 256, 0, stream>>>(latent_Z, sidx,
                                                            zhl, u, v, zb16);
    fused_kernel<<<NSBLK + NDBLK, 256, 0, stream>>>(zhl, u, v, zb16, ei, ej, ne,
                                                    dpart, spart);
    final_kernel<<<1, 256, 0, stream>>>(alpha, dpart, spart, out, ne);
}

// Round 12
// 30.001 us; speedup vs baseline: 2.7119x; 1.0070x over previous
//
#include <hip/hip_runtime.h>
#include <hip/hip_bf16.h>
#include <math.h>

#define NNODES   100000
#define S        8192
#define D        8
#define EPSF     1e-6f
#define LOG2E    1.442695040888963f
#define EPS_S    (LOG2E * EPSF)
#define NT2      256        // 8192/32 tiles per dim

// ws byte offsets
#define ZHL_OFF  0          // 8192 rows x 16 ushort (hi[8]|lo[8]) = 262144 B
#define U_OFF    262144     // 8192 f32
#define V_OFF    294912     // 8192 f32
#define ZB_OFF   327680     // 100000 rows x 8 bf16 = 1.6 MB
#define BK_OFF   1928192    // bucket region (aligned, after zb16)
// bucket region layout (128-B stride each):
//   dbuck[64] doubles   @ BK_OFF
//   sbuck[16] doubles   @ BK_OFF + 64*128
//   cbuck[80] uints     @ BK_OFF + 80*128
//   gdone     uint      @ BK_OFF + 160*128
#define NBUCK_BYTES (161 * 128)

#define NSBLK    256        // sparse blocks
#define NDBLK    1024       // dense blocks = 128 row-pairs x 8
#define NWPP     32         // waves per row-pair

typedef __attribute__((ext_vector_type(8)))  short short8_t;
typedef __attribute__((ext_vector_type(16))) float f32x16;

__device__ __forceinline__ float block_reduce_f(float v, float* sm) {
    #pragma unroll
    for (int off = 32; off > 0; off >>= 1) v += __shfl_down(v, off, 64);
    int lane = threadIdx.x & 63, wid = threadIdx.x >> 6;
    if (lane == 0) sm[wid] = v;
    __syncthreads();
    float s = 0.f;
    if (threadIdx.x == 0) {
        for (int w = 0; w < 4; ++w) s += sm[w];
    }
    return s;
}

// ---- kernel 1: sample-gather (prescaled hi/lo split) + full-Z bf16 copy ----
// Also zeroes the finalize bucket region (node boundary orders it before k2).
__global__ __launch_bounds__(256) void gather_kernel(const float* __restrict__ Z,
                                                     const int* __restrict__ idx,
                                                     ushort* __restrict__ zhl,
                                                     float* __restrict__ u,
                                                     float* __restrict__ v,
                                                     ushort* __restrict__ zb16,
                                                     char* __restrict__ buckets) {
    int gid = blockIdx.x * 256 + threadIdx.x;

    // zero buckets: 161 slots x 128 B; first 161 threads of block 0
    if (blockIdx.x == 0 && threadIdx.x < 161) {
        *(double*)(buckets + threadIdx.x * 128) = 0.0;   // also zeroes the uints
    }

    if (gid < S) {
        int n = idx[gid];
        const float4* zp = (const float4*)(Z + (size_t)n * D);
        float4 a = zp[0], b = zp[1];
        float z[8] = { a.x, a.y, a.z, a.w, b.x, b.y, b.z, b.w };
        float ss = 0.f;
        short8_t h, l;
        #pragma unroll
        for (int k = 0; k < 8; ++k) {
            float zs = LOG2E * z[k];
            ss = fmaf(zs, zs, ss);
            __hip_bfloat16 hb = __float2bfloat16(zs);
            float hf = __bfloat162float(hb);
            __hip_bfloat16 lb = __float2bfloat16(zs - hf);
            h[k] = (short)__builtin_bit_cast(unsigned short, hb);
            l[k] = (short)__builtin_bit_cast(unsigned short, lb);
        }
        *(short8_t*)(zhl + (size_t)gid * 16)     = h;
        *(short8_t*)(zhl + (size_t)gid * 16 + 8) = l;
        u[gid] = ss + 8.f * EPS_S * EPS_S;
        v[gid] = ss;
    }

    if (gid < NNODES) {
        const float4* zp = (const float4*)(Z + (size_t)gid * D);
        float4 a = zp[0], b = zp[1];
        float z[8] = { a.x, a.y, a.z, a.w, b.x, b.y, b.z, b.w };
        short8_t o;
        #pragma unroll
        for (int k = 0; k < 8; ++k) {
            __hip_bfloat16 bb = __float2bfloat16(z[k]);
            o[k] = (short)__builtin_bit_cast(unsigned short, bb);
        }
        *(short8_t*)(zb16 + (size_t)gid * 8) = o;
    }
}

// bf16 row (uint4) -> 8 f32
#define UNPACK8(u4, f)                                        \
    f[0] = __uint_as_float(u4.x << 16);                       \
    f[1] = __uint_as_float(u4.x & 0xffff0000u);               \
    f[2] = __uint_as_float(u4.y << 16);                       \
    f[3] = __uint_as_float(u4.y & 0xffff0000u);               \
    f[4] = __uint_as_float(u4.z << 16);                       \
    f[5] = __uint_as_float(u4.z & 0xffff0000u);               \
    f[6] = __uint_as_float(u4.w << 16);                       \
    f[7] = __uint_as_float(u4.w & 0xffff0000u);

__device__ __forceinline__ float edge_dist4(const uint4* __restrict__ zb,
                                            int4 ia, int4 ib) {
    float acc = 0.f;
    int aidx[4] = { ia.x, ia.y, ia.z, ia.w };
    int bidx[4] = { ib.x, ib.y, ib.z, ib.w };
    #pragma unroll
    for (int q = 0; q < 4; ++q) {
        uint4 ua = zb[aidx[q]];
        uint4 ub = zb[bidx[q]];
        float fa[8], fb[8];
        UNPACK8(ua, fa);
        UNPACK8(ub, fb);
        float s2 = 0.f;
        #pragma unroll
        for (int k = 0; k < 8; ++k) {
            float d = fa[k] - fb[k] + EPSF;
            s2 = fmaf(d, d, s2);
        }
        acc += __builtin_amdgcn_sqrtf(s2);
    }
    return acc;
}

// Sweep `cnt` consecutive 32x32 j-tiles starting at tj0 for fixed i-tile ti.
// Hi/lo exact product via 2 chained MFMAs. Off-diag tiles weight 2, diag 1.
// C/D: col = lane&31, row = (reg&3) + 8*(reg>>2) + 4*(lane>>5).
__device__ __forceinline__ void dense_sweep32(const ushort* __restrict__ zhl,
                                              const float* __restrict__ v,
                                              short8_t afrag, const float4* u4,
                                              int ti, int tj0, int cnt, int c31,
                                              float& ax, float& ay, float& az, float& aw) {
    const ushort* bp = zhl + (size_t)(tj0 * 32 + c31) * 16;
    const float*  vp = v + tj0 * 32 + c31;
    short8_t bh = *(const short8_t*)bp;
    short8_t bl = *(const short8_t*)(bp + 8);
    float    vt = vp[0];
    #pragma unroll 2
    for (int t = 0; t < cnt; ++t) {
        short8_t bhc = bh, blc = bl;
        float    vtc = vt;
        if (t + 1 < cnt) {
            bh = *(const short8_t*)(bp + (size_t)(t + 1) * 512);
            bl = *(const short8_t*)(bp + (size_t)(t + 1) * 512 + 8);
            vt = vp[(t + 1) * 32];
        }
        float w = (tj0 + t == ti) ? 1.f : 2.f;
        f32x16 c = { 0.f, 0.f, 0.f, 0.f, 0.f, 0.f, 0.f, 0.f,
                     0.f, 0.f, 0.f, 0.f, 0.f, 0.f, 0.f, 0.f };
        c = __builtin_amdgcn_mfma_f32_32x32x16_bf16(afrag, bhc, c, 0, 0, 0);
        c = __builtin_amdgcn_mfma_f32_32x32x16_bf16(afrag, blc, c, 0, 0, 0);
        #pragma unroll
        for (int q = 0; q < 4; ++q) {
            float s0 = u4[q].x + vtc, s1 = u4[q].y + vtc;
            float s2 = u4[q].z + vtc, s3 = u4[q].w + vtc;
            float d0 = fmaf(c[4*q+0], -2.f, s0);
            float d1 = fmaf(c[4*q+1], -2.f, s1);
            float d2 = fmaf(c[4*q+2], -2.f, s2);
            float d3 = fmaf(c[4*q+3], -2.f, s3);
            ax = fmaf(w, __builtin_amdgcn_exp2f(-__builtin_amdgcn_sqrtf(__builtin_fabsf(d0))), ax);
            ay = fmaf(w, __builtin_amdgcn_exp2f(-__builtin_amdgcn_sqrtf(__builtin_fabsf(d1))), ay);
            az = fmaf(w, __builtin_amdgcn_exp2f(-__builtin_amdgcn_sqrtf(__builtin_fabsf(d2))), az);
            aw = fmaf(w, __builtin_amdgcn_exp2f(-__builtin_amdgcn_sqrtf(__builtin_fabsf(d3))), aw);
        }
    }
}

// ---- kernel 2: sparse || dense 32x32 triangle; bucketed atomic finalize ----
__global__ __launch_bounds__(256) void fused_kernel(
        const ushort* __restrict__ zhl, const float* __restrict__ u,
        const float* __restrict__ v, const ushort* __restrict__ zb16,
        const int* __restrict__ ei, const int* __restrict__ ej, int ne,
        const float* __restrict__ alpha, char* __restrict__ buckets,
        float* __restrict__ out) {
    __shared__ float red[4];
    __shared__ unsigned composeFlag;
    int tid = threadIdx.x, bx = blockIdx.x;
    float s;

    if (bx < NSBLK) {
        // ---- sparse positive-edge term (bf16 rows, idx-prefetched) ----
        const uint4* zb = (const uint4*)zb16;
        float acc = 0.f;
        int nchunk = ne >> 2;
        int stride = NSBLK * 256;
        int c = bx * 256 + tid;
        if (c < nchunk) {
            int4 ia = ((const int4*)ei)[c];
            int4 ib = ((const int4*)ej)[c];
            while (true) {
                int cn = c + stride;
                int4 ian, ibn;
                bool more = cn < nchunk;
                if (more) {
                    ian = ((const int4*)ei)[cn];
                    ibn = ((const int4*)ej)[cn];
                }
                acc += edge_dist4(zb, ia, ib);
                if (!more) break;
                ia = ian; ib = ibn; c = cn;
            }
        }
        for (int e = (nchunk << 2) + bx * 256 + tid; e < ne; e += stride) {
            uint4 ua = zb[ei[e]];
            uint4 ub = zb[ej[e]];
            float fa[8], fb[8];
            UNPACK8(ua, fa);
            UNPACK8(ub, fb);
            float s2 = 0.f;
            #pragma unroll
            for (int k = 0; k < 8; ++k) {
                float d = fa[k] - fb[k] + EPSF;
                s2 = fmaf(d, d, s2);
            }
            acc += __builtin_amdgcn_sqrtf(s2);
        }
        s = block_reduce_f(acc, red);
    } else {
        // ---- dense term (upper-triangle 32x32 tiles, row-paired) ----
        int dbx  = bx - NSBLK;
        int wave = tid >> 6, lane = tid & 63;
        int g = lane >> 5, c31 = lane & 31;

        int p  = dbx >> 3;                       // row-pair index [0,128)
        int wv = (dbx & 7) * 4 + wave;           // wave within pair [0,32)
        int k0 = (wv * 257) / NWPP;
        int k1 = ((wv + 1) * 257) / NWPP;
        int n1 = NT2 - p;                        // tiles in row ti = p

        float ax = 0.f, ay = 0.f, az = 0.f, aw = 0.f;

        int eA = k1 < n1 ? k1 : n1;
        if (k0 < eA) {
            int ti = p;
            short8_t afrag = *(const short8_t*)(zhl + (size_t)(ti * 32 + c31) * 16 + g * 8);
            float4 u4[4];
            #pragma unroll
            for (int q = 0; q < 4; ++q) u4[q] = *(const float4*)(u + ti * 32 + 8 * q + 4 * g);
            dense_sweep32(zhl, v, afrag, u4, ti, p + k0, eA - k0, c31, ax, ay, az, aw);
        }
        int sB = k0 > n1 ? k0 : n1;
        if (sB < k1) {
            int ti = (NT2 - 1) - p;
            short8_t afrag = *(const short8_t*)(zhl + (size_t)(ti * 32 + c31) * 16 + g * 8);
            float4 u4[4];
            #pragma unroll
            for (int q = 0; q < 4; ++q) u4[q] = *(const float4*)(u + ti * 32 + 8 * q + 4 * g);
            dense_sweep32(zhl, v, afrag, u4, ti, ti + (sB - n1), k1 - sB, c31, ax, ay, az, aw);
        }
        s = block_reduce_f((ax + ay) + (az + aw), red);
    }

    // ---- bucketed finalize: 80 buckets x 16 blocks, <=16-deep atomic chains ----
    double* dbuck = (double*)(buckets);
    double* sbuck = (double*)(buckets + 64 * 128);
    unsigned* gdone = (unsigned*)(buckets + 160 * 128);

    if (tid == 0) {
        int  sparse = (bx < NSBLK);
        int  sid = sparse ? (bx & 15) : ((bx - NSBLK) & 63);
        int  cid = sparse ? (64 + (bx >> 4)) : ((bx - NSBLK) >> 4);
        double* sumslot = sparse ? (double*)((char*)sbuck + sid * 128)
                                 : (double*)((char*)dbuck + sid * 128);
        (void)atomicAdd(sumslot, (double)s);
        __builtin_amdgcn_s_waitcnt(0);                 // sum add complete
        unsigned oc = atomicAdd((unsigned*)(buckets + (80 + cid) * 128), 1u);
        unsigned g = 0xFFFFu;
        if (oc == 15u) {
            __builtin_amdgcn_s_waitcnt(0);
            g = atomicAdd(gdone, 1u);
        }
        composeFlag = (g == 79u) ? 1u : 0u;
    }
    __syncthreads();

    if (composeFlag) {
        // all 1280 sum-adds completed-before their counter incs, which
        // completed-before the 80 gdone incs we observed. Read + compose.
        __shared__ double acc2[2];
        int lane = tid & 63, w = tid >> 6;
        double val = 0.0;
        if (w == 0) val = atomicAdd((double*)((char*)dbuck + lane * 128), 0.0);
        else if (w == 1 && lane < 16) val = atomicAdd((double*)((char*)sbuck + lane * 128), 0.0);
        #pragma unroll
        for (int off = 32; off > 0; off >>= 1) val += __shfl_down(val, off, 64);
        if (w == 0 && lane == 0) acc2[0] = val;
        if (w == 1 && lane == 0) acc2[1] = val;
        __syncthreads();
        if (tid == 0) {
            double Dsum = acc2[0], Ssum = acc2[1];
            // diagonal entries are exp(-sqrt(8)*eps); subtract exactly
            double trace = (double)S * exp(-sqrt(8.0) * (double)EPSF);
            double offdiag = Dsum - trace;
            double a = (double)alpha[0];
            double z_pdist2 = (double)ne * a - Ssum;
            double z_pdist1 = exp(a) * 0.5 * 7.3890560989306495 * offdiag;
            out[0] = (float)(z_pdist2 - z_pdist1);
        }
    }
}

extern "C" void kernel_launch(void* const* d_in, const int* in_sizes, int n_in,
                              void* d_out, int out_size, void* d_ws, size_t ws_size,
                              hipStream_t stream) {
    const float* latent_Z = (const float*)d_in[0];
    const float* alpha    = (const float*)d_in[1];
    const int*   sidx     = (const int*)d_in[2];
    const int*   ei       = (const int*)d_in[3];
    const int*   ej       = (const int*)d_in[4];
    int ne = in_sizes[3];
    float* out = (float*)d_out;
    char*  ws  = (char*)d_ws;

    ushort* zhl   = (ushort*)(ws + ZHL_OFF);
    float*  u     = (float*)(ws + U_OFF);
    float*  v     = (float*)(ws + V_OFF);
    ushort* zb16  = (ushort*)(ws + ZB_OFF);
    char*   bk    = ws + BK_OFF;

    gather_kernel<<<(NNODES + 255) / 256, 256, 0, stream>>>(latent_Z, sidx,
                                                            zhl, u, v, zb16, bk);
    fused_kernel<<<NSBLK + NDBLK, 256, 0, stream>>>(zhl, u, v, zb16, ei, ej, ne,
                                                    alpha, bk, out);
}